// Round 1
// baseline (2116.111 us; speedup 1.0000x reference)
//
#include <hip/hip_runtime.h>
#include <cstddef>

#define D_MODEL 1024
#define D_IN    2048
#define D_STATE 16
#define CONV_D  4
#define BATCH   4
#define SEQ     2048
#define NROWS   (BATCH * SEQ)   // 8192

// ---------------- RMSNorm: one block per row (1024 floats), 256 threads ----------------
__global__ void rmsnorm_kernel(const float* __restrict__ x,
                               const float* __restrict__ w,
                               float* __restrict__ h) {
    const int row = blockIdx.x;
    const float* xr = x + (size_t)row * D_MODEL;
    float* hr = h + (size_t)row * D_MODEL;
    const int tid = threadIdx.x;  // 0..255, each handles 4 floats

    float4 v = reinterpret_cast<const float4*>(xr)[tid];
    float ss = v.x * v.x + v.y * v.y + v.z * v.z + v.w * v.w;

    // wave64 reduce
    #pragma unroll
    for (int off = 32; off > 0; off >>= 1) ss += __shfl_down(ss, off, 64);

    __shared__ float wsum[4];
    const int wid = tid >> 6, lane = tid & 63;
    if (lane == 0) wsum[wid] = ss;
    __syncthreads();
    const float tot = wsum[0] + wsum[1] + wsum[2] + wsum[3];
    const float scale = rsqrtf(tot * (1.0f / D_MODEL) + 1e-6f);

    float4 wv = reinterpret_cast<const float4*>(w)[tid];
    float4 o;
    o.x = v.x * scale * wv.x;
    o.y = v.y * scale * wv.y;
    o.z = v.z * scale * wv.z;
    o.w = v.w * scale * wv.w;
    reinterpret_cast<float4*>(hr)[tid] = o;
}

// ---------------- fp32 tiled GEMM: C[M,N] = A[M,K] @ B[K,N] + bias (+ resid) ----------------
// 64x64 tile, BK=16, 256 threads, 4x4 per thread.
template <int M, int N, int K>
__global__ void gemm_kernel(const float* __restrict__ A,
                            const float* __restrict__ B,
                            const float* __restrict__ bias,
                            const float* __restrict__ resid,
                            float* __restrict__ C) {
    __shared__ float As[64][16];
    __shared__ float Bs[16][64];

    const int t = threadIdx.x;          // 0..255
    const int tx = t & 15;              // 0..15 -> 4 cols each
    const int ty = t >> 4;              // 0..15 -> 4 rows each
    const int row0 = blockIdx.y * 64;
    const int col0 = blockIdx.x * 64;

    float acc[4][4];
    #pragma unroll
    for (int i = 0; i < 4; ++i)
        #pragma unroll
        for (int j = 0; j < 4; ++j) acc[i][j] = 0.f;

    for (int k0 = 0; k0 < K; k0 += 16) {
        // Load A tile: 64 rows x 16 cols, one float4 per thread
        {
            const int ar = t >> 2;          // 0..63
            const int ac = (t & 3) * 4;     // 0,4,8,12
            float4 av = *reinterpret_cast<const float4*>(
                &A[(size_t)(row0 + ar) * K + k0 + ac]);
            As[ar][ac + 0] = av.x;
            As[ar][ac + 1] = av.y;
            As[ar][ac + 2] = av.z;
            As[ar][ac + 3] = av.w;
        }
        // Load B tile: 16 rows x 64 cols, one float4 per thread
        {
            const int br = t >> 4;          // 0..15
            const int bc = (t & 15) * 4;    // 0..60
            float4 bv = *reinterpret_cast<const float4*>(
                &B[(size_t)(k0 + br) * N + col0 + bc]);
            *reinterpret_cast<float4*>(&Bs[br][bc]) = bv;
        }
        __syncthreads();

        #pragma unroll
        for (int kk = 0; kk < 16; ++kk) {
            float a[4], b[4];
            #pragma unroll
            for (int i = 0; i < 4; ++i) a[i] = As[ty * 4 + i][kk];
            #pragma unroll
            for (int j = 0; j < 4; ++j) b[j] = Bs[kk][tx * 4 + j];
            #pragma unroll
            for (int i = 0; i < 4; ++i)
                #pragma unroll
                for (int j = 0; j < 4; ++j)
                    acc[i][j] = fmaf(a[i], b[j], acc[i][j]);
        }
        __syncthreads();
    }

    // Epilogue
    const int ccol = col0 + tx * 4;
    float4 bb = *reinterpret_cast<const float4*>(&bias[ccol]);
    #pragma unroll
    for (int i = 0; i < 4; ++i) {
        const int row = row0 + ty * 4 + i;
        float4 o;
        o.x = acc[i][0] + bb.x;
        o.y = acc[i][1] + bb.y;
        o.z = acc[i][2] + bb.z;
        o.w = acc[i][3] + bb.w;
        if (resid) {
            float4 r = *reinterpret_cast<const float4*>(&resid[(size_t)row * N + ccol]);
            o.x += r.x; o.y += r.y; o.z += r.z; o.w += r.w;
        }
        *reinterpret_cast<float4*>(&C[(size_t)row * N + ccol]) = o;
    }
}

// ---------------- Fused depthwise causal conv(4) + SSM scan ----------------
// One wave (64 threads) per channel d. lane = b*16 + s.
// hc[b,d,s] kept in a register; A[d] column s in 16 registers.
__global__ void conv_scan_kernel(const float* __restrict__ u0,
                                 const float* __restrict__ conv_w,
                                 const float* __restrict__ conv_b,
                                 const float* __restrict__ A,
                                 const float* __restrict__ Bm,
                                 const float* __restrict__ Cm,
                                 float* __restrict__ y) {
    const int d = blockIdx.x;        // 0..2047
    const int lane = threadIdx.x;    // 0..63
    const int b = lane >> 4;
    const int s = lane & 15;
    const int base = lane & 48;      // b*16

    float a_col[16];
    #pragma unroll
    for (int r = 0; r < 16; ++r)
        a_col[r] = A[(size_t)d * 256 + r * 16 + s];   // A[d][r][s]

    const float bv = Bm[d * 16 + s];      // Bm[d][s][0]
    const float cv = Cm[d * 16 + s];      // Cm[d][0][s]
    const float w0 = conv_w[d * 4 + 0];
    const float w1 = conv_w[d * 4 + 1];
    const float w2 = conv_w[d * 4 + 2];
    const float w3 = conv_w[d * 4 + 3];
    const float cb = conv_b[d];

    float hc = 0.f;
    float p1 = 0.f, p2 = 0.f, p3 = 0.f;   // u0[t-1], u0[t-2], u0[t-3]

    const float* up = u0 + (size_t)b * SEQ * D_IN + d;
    float* yp = y + (size_t)b * SEQ * D_IN + d;

    for (int t = 0; t < SEQ; ++t) {
        const float xin = up[(size_t)t * D_IN];
        float uval = fmaf(w3, xin, fmaf(w2, p1, fmaf(w1, p2, fmaf(w0, p3, cb))));
        p3 = p2; p2 = p1; p1 = xin;

        // hc_new[s] = sum_r hc[r] * A[d][r][s]  (4 partial chains to cut fma latency)
        float hn0 = 0.f, hn1 = 0.f, hn2 = 0.f, hn3 = 0.f;
        #pragma unroll
        for (int r = 0; r < 16; r += 4) {
            hn0 = fmaf(__shfl(hc, base + r + 0, 64), a_col[r + 0], hn0);
            hn1 = fmaf(__shfl(hc, base + r + 1, 64), a_col[r + 1], hn1);
            hn2 = fmaf(__shfl(hc, base + r + 2, 64), a_col[r + 2], hn2);
            hn3 = fmaf(__shfl(hc, base + r + 3, 64), a_col[r + 3], hn3);
        }
        hc = fmaf(uval, bv, (hn0 + hn1) + (hn2 + hn3));

        // y[b,t,d] = sum_s hc[s] * C[d][s]
        float pv = hc * cv;
        pv += __shfl_xor(pv, 1, 64);
        pv += __shfl_xor(pv, 2, 64);
        pv += __shfl_xor(pv, 4, 64);
        pv += __shfl_xor(pv, 8, 64);
        if (s == 0) yp[(size_t)t * D_IN] = pv;
    }
}

extern "C" void kernel_launch(void* const* d_in, const int* in_sizes, int n_in,
                              void* d_out, int out_size, void* d_ws, size_t ws_size,
                              hipStream_t stream) {
    const float* x      = (const float*)d_in[0];
    const float* norm_w = (const float*)d_in[1];
    const float* Win    = (const float*)d_in[2];
    const float* b_in   = (const float*)d_in[3];
    const float* conv_w = (const float*)d_in[4];
    const float* conv_b = (const float*)d_in[5];
    const float* A      = (const float*)d_in[6];
    const float* Bm     = (const float*)d_in[7];
    const float* Cm     = (const float*)d_in[8];
    const float* Wout   = (const float*)d_in[9];
    const float* b_out  = (const float*)d_in[10];
    float* out = (float*)d_out;

    // Workspace layout: u0 (64MB) | y (64MB). h reuses d_out (32MB).
    float* u0 = (float*)d_ws;
    float* yb = (float*)((char*)d_ws + (size_t)NROWS * D_IN * sizeof(float));
    float* h  = out;

    // 1) RMSNorm: x -> h (in d_out)
    rmsnorm_kernel<<<NROWS, 256, 0, stream>>>(x, norm_w, h);

    // 2) u0 = h @ Win + b_in
    {
        dim3 grid(D_IN / 64, NROWS / 64);
        gemm_kernel<NROWS, D_IN, D_MODEL><<<grid, 256, 0, stream>>>(
            h, Win, b_in, nullptr, u0);
    }

    // 3) conv(4, causal, depthwise) fused with SSM scan: u0 -> yb
    conv_scan_kernel<<<D_IN, 64, 0, stream>>>(u0, conv_w, conv_b, A, Bm, Cm, yb);

    // 4) out = yb @ Wout + b_out + x
    {
        dim3 grid(D_MODEL / 64, NROWS / 64);
        gemm_kernel<NROWS, D_MODEL, D_IN><<<grid, 256, 0, stream>>>(
            yb, Wout, b_out, x, out);
    }
}

// Round 2
// 1168.313 us; speedup vs baseline: 1.8113x; 1.8113x over previous
//
#include <hip/hip_runtime.h>
#include <cstddef>

#define D_MODEL 1024
#define D_IN    2048
#define D_STATE 16
#define CONV_D  4
#define BATCH   4
#define SEQ     2048
#define NROWS   (BATCH * SEQ)   // 8192

// ---------------- RMSNorm: one block per row (1024 floats), 256 threads ----------------
__global__ void rmsnorm_kernel(const float* __restrict__ x,
                               const float* __restrict__ w,
                               float* __restrict__ h) {
    const int row = blockIdx.x;
    const float* xr = x + (size_t)row * D_MODEL;
    float* hr = h + (size_t)row * D_MODEL;
    const int tid = threadIdx.x;  // 0..255, each handles 4 floats

    float4 v = reinterpret_cast<const float4*>(xr)[tid];
    float ss = v.x * v.x + v.y * v.y + v.z * v.z + v.w * v.w;

    #pragma unroll
    for (int off = 32; off > 0; off >>= 1) ss += __shfl_down(ss, off, 64);

    __shared__ float wsum[4];
    const int wid = tid >> 6, lane = tid & 63;
    if (lane == 0) wsum[wid] = ss;
    __syncthreads();
    const float tot = wsum[0] + wsum[1] + wsum[2] + wsum[3];
    const float scale = rsqrtf(tot * (1.0f / D_MODEL) + 1e-6f);

    float4 wv = reinterpret_cast<const float4*>(w)[tid];
    float4 o;
    o.x = v.x * scale * wv.x;
    o.y = v.y * scale * wv.y;
    o.z = v.z * scale * wv.z;
    o.w = v.w * scale * wv.w;
    reinterpret_cast<float4*>(hr)[tid] = o;
}

// ---------------- GEMM1: u0T[b][d][s] = (h @ Win + b_in) transposed-store ----------------
// A = h [8192][1024] normal, B = Win [1024][2048] normal, 64x64 tile, BK=16.
__global__ void gemm1_kernel(const float* __restrict__ A,
                             const float* __restrict__ B,
                             const float* __restrict__ bias,
                             float* __restrict__ u0T) {
    __shared__ float As[64][16];
    __shared__ float Bs[16][64];
    __shared__ float Ts[64][65];   // [d_local][s_local]

    const int t = threadIdx.x;
    const int tx = t & 15;
    const int ty = t >> 4;
    const int row0 = blockIdx.y * 64;   // (b,s) rows
    const int col0 = blockIdx.x * 64;   // d cols

    float acc[4][4];
    #pragma unroll
    for (int i = 0; i < 4; ++i)
        #pragma unroll
        for (int j = 0; j < 4; ++j) acc[i][j] = 0.f;

    for (int k0 = 0; k0 < D_MODEL; k0 += 16) {
        {
            const int ar = t >> 2;
            const int ac = (t & 3) * 4;
            float4 av = *reinterpret_cast<const float4*>(
                &A[(size_t)(row0 + ar) * D_MODEL + k0 + ac]);
            As[ar][ac + 0] = av.x; As[ar][ac + 1] = av.y;
            As[ar][ac + 2] = av.z; As[ar][ac + 3] = av.w;
        }
        {
            const int br = t >> 4;
            const int bc = (t & 15) * 4;
            float4 bv = *reinterpret_cast<const float4*>(
                &B[(size_t)(k0 + br) * D_IN + col0 + bc]);
            *reinterpret_cast<float4*>(&Bs[br][bc]) = bv;
        }
        __syncthreads();
        #pragma unroll
        for (int kk = 0; kk < 16; ++kk) {
            float a[4], b[4];
            #pragma unroll
            for (int i = 0; i < 4; ++i) a[i] = As[ty * 4 + i][kk];
            #pragma unroll
            for (int j = 0; j < 4; ++j) b[j] = Bs[kk][tx * 4 + j];
            #pragma unroll
            for (int i = 0; i < 4; ++i)
                #pragma unroll
                for (int j = 0; j < 4; ++j)
                    acc[i][j] = fmaf(a[i], b[j], acc[i][j]);
        }
        __syncthreads();
    }

    // Transposed epilogue: stage [d][s] tile in LDS, then coalesced store along s.
    #pragma unroll
    for (int j = 0; j < 4; ++j) {
        const float bb = bias[col0 + tx * 4 + j];
        #pragma unroll
        for (int i = 0; i < 4; ++i)
            Ts[tx * 4 + j][ty * 4 + i] = acc[i][j] + bb;
    }
    __syncthreads();

    const int b      = row0 >> 11;       // row0 / SEQ
    const int s_base = row0 & (SEQ - 1);
    const int d_local = t >> 2;          // 0..63
    const int s_off   = (t & 3) * 16;    // 0,16,32,48
    float* dst = u0T + (size_t)b * D_IN * SEQ + (size_t)(col0 + d_local) * SEQ
                 + s_base + s_off;
    #pragma unroll
    for (int c = 0; c < 4; ++c) {
        float4 v = *reinterpret_cast<const float4*>(&Ts[d_local][s_off + c * 4]);
        *reinterpret_cast<float4*>(&dst[c * 4]) = v;
    }
}

// ---------------- GEMM2: out = yT-gemm + b_out + x ----------------
// A_eff[row=(b,s)][k=d] = yT[b][d][s] (transposed load), B = Wout [2048][1024].
__global__ void gemm2_kernel(const float* __restrict__ yT,
                             const float* __restrict__ B,
                             const float* __restrict__ bias,
                             const float* __restrict__ resid,
                             float* __restrict__ C) {
    __shared__ float As[64][17];
    __shared__ float Bs[16][64];

    const int t = threadIdx.x;
    const int tx = t & 15;
    const int ty = t >> 4;
    const int row0 = blockIdx.y * 64;
    const int col0 = blockIdx.x * 64;
    const int b      = row0 >> 11;
    const int s0     = row0 & (SEQ - 1);

    float acc[4][4];
    #pragma unroll
    for (int i = 0; i < 4; ++i)
        #pragma unroll
        for (int j = 0; j < 4; ++j) acc[i][j] = 0.f;

    for (int k0 = 0; k0 < D_IN; k0 += 16) {
        // A tile: As[s_local][kk] = yT[b][k0+kk][s0+s_local]; coalesced along s.
        {
            const int kk = t >> 4;          // 0..15
            const int sl = (t & 15) * 4;    // 0..60
            float4 v = *reinterpret_cast<const float4*>(
                &yT[(size_t)b * D_IN * SEQ + (size_t)(k0 + kk) * SEQ + s0 + sl]);
            As[sl + 0][kk] = v.x; As[sl + 1][kk] = v.y;
            As[sl + 2][kk] = v.z; As[sl + 3][kk] = v.w;
        }
        {
            const int br = t >> 4;
            const int bc = (t & 15) * 4;
            float4 bv = *reinterpret_cast<const float4*>(
                &B[(size_t)(k0 + br) * D_MODEL + col0 + bc]);
            *reinterpret_cast<float4*>(&Bs[br][bc]) = bv;
        }
        __syncthreads();
        #pragma unroll
        for (int kk = 0; kk < 16; ++kk) {
            float a[4], b2[4];
            #pragma unroll
            for (int i = 0; i < 4; ++i) a[i] = As[ty * 4 + i][kk];
            #pragma unroll
            for (int j = 0; j < 4; ++j) b2[j] = Bs[kk][tx * 4 + j];
            #pragma unroll
            for (int i = 0; i < 4; ++i)
                #pragma unroll
                for (int j = 0; j < 4; ++j)
                    acc[i][j] = fmaf(a[i], b2[j], acc[i][j]);
        }
        __syncthreads();
    }

    const int ccol = col0 + tx * 4;
    float4 bb = *reinterpret_cast<const float4*>(&bias[ccol]);
    #pragma unroll
    for (int i = 0; i < 4; ++i) {
        const int row = row0 + ty * 4 + i;
        float4 r = *reinterpret_cast<const float4*>(&resid[(size_t)row * D_MODEL + ccol]);
        float4 o;
        o.x = acc[i][0] + bb.x + r.x;
        o.y = acc[i][1] + bb.y + r.y;
        o.z = acc[i][2] + bb.z + r.z;
        o.w = acc[i][3] + bb.w + r.w;
        *reinterpret_cast<float4*>(&C[(size_t)row * D_MODEL + ccol]) = o;
    }
}

// ---------------- Prep: per-channel scan matrices ----------------
// mats[d][0][s][r] = Pt = A^16[r][s]
// mats[d][1][s][i] = Gt = (Bv·A^{15-i})[s]      (coeff of u_{t0+1+i} in hc update)
// mats[d][2][s][r] = Wt = (A^{s+1}·Cv)[r]       (coeff of hc0[r] in y at offset s)
// mats[d][3][s][i] = Qt = (i<=s) ? Bv·A^{s-i}·Cv : 0
__global__ void prep_kernel(const float* __restrict__ A,
                            const float* __restrict__ Bm,
                            const float* __restrict__ Cm,
                            float* __restrict__ mats) {
    const int d = blockIdx.x;
    const int t = threadIdx.x;       // 0..255
    const int r = t >> 4, sc = t & 15;

    __shared__ float Ash[16][17];
    __shared__ float Mcur[16][17];
    __shared__ float Bv[16], Cv[16], gs[16], cd[16];

    Ash[r][sc] = A[(size_t)d * 256 + r * 16 + sc];
    if (t < 16) { Bv[t] = Bm[d * 16 + t]; Cv[t] = Cm[d * 16 + t]; }
    Mcur[r][sc] = (r == sc) ? 1.f : 0.f;
    __syncthreads();

    float* md = mats + (size_t)d * 1024;

    for (int m = 0; m <= 16; ++m) {
        float g = 0.f, wv = 0.f, acc = 0.f;
        if (m <= 15 && t < 16) {
            #pragma unroll
            for (int rr = 0; rr < 16; ++rr) g = fmaf(Bv[rr], Mcur[rr][t], g);
        }
        if (m >= 1 && sc == 0) {
            #pragma unroll
            for (int ss = 0; ss < 16; ++ss) wv = fmaf(Mcur[r][ss], Cv[ss], wv);
        }
        if (m == 16) md[0 + sc * 16 + r] = Mcur[r][sc];          // Pt
        if (m < 16) {
            #pragma unroll
            for (int k = 0; k < 16; ++k) acc = fmaf(Mcur[r][k], Ash[k][sc], acc);
        }
        if (m <= 15 && t < 16) { md[256 + t * 16 + (15 - m)] = g; gs[t] = g; }
        if (m >= 1 && sc == 0) md[512 + (m - 1) * 16 + r] = wv;  // Wt
        __syncthreads();
        if (m <= 15 && t == 0) {
            float c = 0.f;
            #pragma unroll
            for (int ss = 0; ss < 16; ++ss) c = fmaf(gs[ss], Cv[ss], c);
            cd[m] = c;
        }
        if (m < 16) Mcur[r][sc] = acc;
        __syncthreads();
    }
    // Qt: thread (j=r, i=sc)
    md[768 + r * 16 + sc] = (sc <= r) ? cd[r - sc] : 0.f;
}

// ---------------- Fused conv + scan, 16 timesteps per macro-step, IN-PLACE ----------------
// One wave per channel d; lane = b*16 + s. u layout [b][d][t]; y overwrites u.
__global__ void scan16_kernel(float* __restrict__ u,
                              const float* __restrict__ conv_w,
                              const float* __restrict__ conv_b,
                              const float* __restrict__ mats) {
    const int d = blockIdx.x;
    const int lane = threadIdx.x;   // 0..63
    const int s = lane & 15;
    const int b = lane >> 4;
    const int base = lane & 48;

    const float* md = mats + (size_t)d * 1024;
    float Pt[16], Gt[16], Wt[16], Qt[16];
    #pragma unroll
    for (int q = 0; q < 4; ++q) {
        float4 v;
        v = reinterpret_cast<const float4*>(md + 0   + s * 16)[q];
        Pt[4*q+0]=v.x; Pt[4*q+1]=v.y; Pt[4*q+2]=v.z; Pt[4*q+3]=v.w;
        v = reinterpret_cast<const float4*>(md + 256 + s * 16)[q];
        Gt[4*q+0]=v.x; Gt[4*q+1]=v.y; Gt[4*q+2]=v.z; Gt[4*q+3]=v.w;
        v = reinterpret_cast<const float4*>(md + 512 + s * 16)[q];
        Wt[4*q+0]=v.x; Wt[4*q+1]=v.y; Wt[4*q+2]=v.z; Wt[4*q+3]=v.w;
        v = reinterpret_cast<const float4*>(md + 768 + s * 16)[q];
        Qt[4*q+0]=v.x; Qt[4*q+1]=v.y; Qt[4*q+2]=v.z; Qt[4*q+3]=v.w;
    }

    const float w0 = conv_w[d * 4 + 0];
    const float w1 = conv_w[d * 4 + 1];
    const float w2 = conv_w[d * 4 + 2];
    const float w3 = conv_w[d * 4 + 3];
    const float cb = conv_b[d];

    float hc = 0.f;
    float c1 = 0.f, c2 = 0.f, c3 = 0.f;  // x at t0, t0-1, t0-2 of previous block

    float* up = u + (size_t)b * D_IN * SEQ + (size_t)d * SEQ;

    for (int m = 0; m < SEQ / 16; ++m) {
        const float x = up[16 * m + s];

        // conv window via intra-group shuffles + carries
        float xm1 = __shfl(x, (lane - 1) & 63, 64);
        float xm2 = __shfl(x, (lane - 2) & 63, 64);
        float xm3 = __shfl(x, (lane - 3) & 63, 64);
        if (s == 0) xm1 = c1;
        if (s <= 1) xm2 = (s == 1) ? c1 : c2;
        if (s <= 2) xm3 = (s == 2) ? c1 : ((s == 1) ? c2 : c3);
        const float uval = fmaf(w3, x, fmaf(w2, xm1, fmaf(w1, xm2, fmaf(w0, xm3, cb))));

        // carries for next block (x at s=15,14,13)
        const float n1 = __shfl(x, base + 15, 64);
        const float n2 = __shfl(x, base + 14, 64);
        const float n3 = __shfl(x, base + 13, 64);

        // hn[s] = hc·P + u·G ; yv(j=s+1) = hc·W + u·Q
        float hnA = 0.f, hnB = 0.f, yvA = 0.f, yvB = 0.f;
        #pragma unroll
        for (int rq = 0; rq < 8; ++rq) {
            const float h0 = __shfl(hc, base + 2 * rq + 0, 64);
            const float h1 = __shfl(hc, base + 2 * rq + 1, 64);
            hnA = fmaf(h0, Pt[2 * rq + 0], hnA);
            hnB = fmaf(h1, Pt[2 * rq + 1], hnB);
            yvA = fmaf(h0, Wt[2 * rq + 0], yvA);
            yvB = fmaf(h1, Wt[2 * rq + 1], yvB);
        }
        #pragma unroll
        for (int iq = 0; iq < 8; ++iq) {
            const float u0 = __shfl(uval, base + 2 * iq + 0, 64);
            const float u1 = __shfl(uval, base + 2 * iq + 1, 64);
            hnA = fmaf(u0, Gt[2 * iq + 0], hnA);
            hnB = fmaf(u1, Gt[2 * iq + 1], hnB);
            yvA = fmaf(u0, Qt[2 * iq + 0], yvA);
            yvB = fmaf(u1, Qt[2 * iq + 1], yvB);
        }
        hc = hnA + hnB;
        up[16 * m + s] = yvA + yvB;   // y_{16m+s}, in-place
        c1 = n1; c2 = n2; c3 = n3;
    }
}

extern "C" void kernel_launch(void* const* d_in, const int* in_sizes, int n_in,
                              void* d_out, int out_size, void* d_ws, size_t ws_size,
                              hipStream_t stream) {
    const float* x      = (const float*)d_in[0];
    const float* norm_w = (const float*)d_in[1];
    const float* Win    = (const float*)d_in[2];
    const float* b_in   = (const float*)d_in[3];
    const float* conv_w = (const float*)d_in[4];
    const float* conv_b = (const float*)d_in[5];
    const float* A      = (const float*)d_in[6];
    const float* Bm     = (const float*)d_in[7];
    const float* Cm     = (const float*)d_in[8];
    const float* Wout   = (const float*)d_in[9];
    const float* b_out  = (const float*)d_in[10];
    float* out = (float*)d_out;

    // ws layout: u0T/yT (in-place, 64MB) | mats (8MB)
    float* u0T  = (float*)d_ws;
    float* mats = (float*)((char*)d_ws + (size_t)BATCH * D_IN * SEQ * sizeof(float));
    float* h    = out;   // d_out reused as scratch for h (dead before GEMM2 writes)

    // 0) per-channel scan matrices (independent of data path)
    prep_kernel<<<D_IN, 256, 0, stream>>>(A, Bm, Cm, mats);

    // 1) RMSNorm: x -> h
    rmsnorm_kernel<<<NROWS, 256, 0, stream>>>(x, norm_w, h);

    // 2) u0T[b][d][s] = h @ Win + b_in (transposed store)
    {
        dim3 grid(D_IN / 64, NROWS / 64);
        gemm1_kernel<<<grid, 256, 0, stream>>>(h, Win, b_in, u0T);
    }

    // 3) conv + scan, blocked by 16, in-place u0T -> yT
    scan16_kernel<<<D_IN, 64, 0, stream>>>(u0T, conv_w, conv_b, mats);

    // 4) out = yT-gemm @ Wout + b_out + x
    {
        dim3 grid(D_MODEL / 64, NROWS / 64);
        gemm2_kernel<<<grid, 256, 0, stream>>>(u0T, Wout, b_out, x, out);
    }
}

// Round 4
// 421.767 us; speedup vs baseline: 5.0172x; 2.7700x over previous
//
#include <hip/hip_runtime.h>
#include <cstddef>

#define D_MODEL 1024
#define D_IN    2048
#define D_STATE 16
#define CONV_D  4
#define BATCH   4
#define SEQ     2048
#define NROWS   (BATCH * SEQ)   // 8192
#define BK      32

typedef __attribute__((ext_vector_type(8))) short bf16x8;
typedef __attribute__((ext_vector_type(4))) float f32x4;

// Cheap exact split: f = bf16(hi) + lo, hi truncated, residual exact in fp32,
// lo truncated to bf16 (net input error ~2^-16 relative).
__device__ inline void split_bf16(float f, short& hi, short& lo) {
    unsigned int u = __float_as_uint(f);
    hi = (short)(u >> 16);
    float fhi = __uint_as_float(u & 0xFFFF0000u);
    lo = (short)(__float_as_uint(f - fhi) >> 16);
}

// ---------------- RMSNorm -> bf16 hi/lo ----------------
__global__ void rmsnorm_kernel(const float* __restrict__ x,
                               const float* __restrict__ w,
                               unsigned short* __restrict__ hh,
                               unsigned short* __restrict__ hl) {
    const int row = blockIdx.x;
    const float* xr = x + (size_t)row * D_MODEL;
    const int tid = threadIdx.x;  // 0..255

    float4 v = reinterpret_cast<const float4*>(xr)[tid];
    float ss = v.x * v.x + v.y * v.y + v.z * v.z + v.w * v.w;
    #pragma unroll
    for (int off = 32; off > 0; off >>= 1) ss += __shfl_down(ss, off, 64);

    __shared__ float wsum[4];
    const int wid = tid >> 6, lane = tid & 63;
    if (lane == 0) wsum[wid] = ss;
    __syncthreads();
    const float tot = wsum[0] + wsum[1] + wsum[2] + wsum[3];
    const float scale = rsqrtf(tot * (1.0f / D_MODEL) + 1e-6f);

    float4 wv = reinterpret_cast<const float4*>(w)[tid];
    float o[4] = { v.x * scale * wv.x, v.y * scale * wv.y,
                   v.z * scale * wv.z, v.w * scale * wv.w };
    short4 oh, ol;
    split_bf16(o[0], oh.x, ol.x);
    split_bf16(o[1], oh.y, ol.y);
    split_bf16(o[2], oh.z, ol.z);
    split_bf16(o[3], oh.w, ol.w);
    *reinterpret_cast<short4*>(&hh[(size_t)row * D_MODEL + tid * 4]) = oh;
    *reinterpret_cast<short4*>(&hl[(size_t)row * D_MODEL + tid * 4]) = ol;
}

// ---------------- transpose + split-cast: in[R][C] f32 -> out[c][R] bf16 hi/lo ----------
// FIXED (R3 bug): write phase now covers the full 64x64 tile (512 bf16x8 groups,
// 2 per thread); previous version wrote only rows 0..31 of each tile.
__global__ void transpose_cast_kernel(const float* __restrict__ in,
                                      unsigned short* __restrict__ oh,
                                      unsigned short* __restrict__ ol,
                                      int R, int C) {
    __shared__ float T[64][65];
    const int z = blockIdx.z;
    const int r0 = blockIdx.y * 64, c0 = blockIdx.x * 64;
    const int t = threadIdx.x;
    const float* src = in + (size_t)z * R * C;

    #pragma unroll
    for (int i = 0; i < 4; ++i) {
        const int r = (t >> 4) + i * 16;
        float4 v = *reinterpret_cast<const float4*>(
            &src[(size_t)(r0 + r) * C + c0 + (t & 15) * 4]);
        T[r][(t & 15) * 4 + 0] = v.x;
        T[r][(t & 15) * 4 + 1] = v.y;
        T[r][(t & 15) * 4 + 2] = v.z;
        T[r][(t & 15) * 4 + 3] = v.w;
    }
    __syncthreads();

    #pragma unroll
    for (int g = 0; g < 2; ++g) {
        const int idx = t + g * 256;   // 0..511
        const int c  = idx >> 3;       // 0..63
        const int rg = idx & 7;        // 0..7 -> rows rg*8..rg*8+7
        bf16x8 vh, vl;
        #pragma unroll
        for (int e = 0; e < 8; ++e) {
            short h, l;
            split_bf16(T[rg * 8 + e][c], h, l);
            vh[e] = h; vl[e] = l;
        }
        const size_t ob = ((size_t)z * C + c0 + c) * R + r0 + rg * 8;
        *reinterpret_cast<bf16x8*>(&oh[ob]) = vh;
        *reinterpret_cast<bf16x8*>(&ol[ob]) = vl;
    }
}

// ---------------- GEMM1 (MFMA, split-bf16): u0T[b][d][s] = h @ Win + b_in ----------------
// Computes the transposed tile directly: "A"-operand rows = d (Wt = Win^T, pre-split),
// "B"-operand rows = m=(b,s) (Hh/Hl). D-tile [d][m], coalesced stores along s.
__global__ __launch_bounds__(256) void gemm1_mfma(
    const unsigned short* __restrict__ Wth, const unsigned short* __restrict__ Wtl, // [2048][1024]
    const unsigned short* __restrict__ Hh,  const unsigned short* __restrict__ Hl,  // [8192][1024]
    const float* __restrict__ bias,   // b_in[d]
    float* __restrict__ u0T) {
    __shared__ bf16x8 Ah[512], Al[512], Bh[512], Bl[512];  // [128 rows][4 k-slots]

    const int t = threadIdx.x;
    const int w = t >> 6, lane = t & 63;
    const int lr = lane & 15, kb = lane >> 4;
    const int wr = (w >> 1) * 64;   // d quadrant
    const int wc = (w & 1) * 64;    // m quadrant
    const int d0 = blockIdx.x * 128;
    const int m0 = blockIdx.y * 128;
    const int sm = t >> 2, sslot = t & 3;

    f32x4 acc[4][4];
    #pragma unroll
    for (int i = 0; i < 4; ++i)
        #pragma unroll
        for (int j = 0; j < 4; ++j) acc[i][j] = (f32x4)(0.f);

    for (int k0 = 0; k0 < D_MODEL; k0 += BK) {
        #pragma unroll
        for (int h = 0; h < 2; ++h) {
            const int m = sm + h * 64;
            const int idx = m * 4 + (sslot ^ ((m >> 1) & 3));
            const size_t ga = (size_t)(d0 + m) * D_MODEL + k0 + sslot * 8;
            Ah[idx] = *reinterpret_cast<const bf16x8*>(Wth + ga);
            Al[idx] = *reinterpret_cast<const bf16x8*>(Wtl + ga);
            const size_t gb = (size_t)(m0 + m) * D_MODEL + k0 + sslot * 8;
            Bh[idx] = *reinterpret_cast<const bf16x8*>(Hh + gb);
            Bl[idx] = *reinterpret_cast<const bf16x8*>(Hl + gb);
        }
        __syncthreads();

        bf16x8 afh[4], afl[4], bfh[4], bfl[4];
        #pragma unroll
        for (int i = 0; i < 4; ++i) {
            const int m = wr + i * 16 + lr;
            const int ia = m * 4 + (kb ^ ((m >> 1) & 3));
            afh[i] = Ah[ia]; afl[i] = Al[ia];
            const int n = wc + i * 16 + lr;
            const int ib = n * 4 + (kb ^ ((n >> 1) & 3));
            bfh[i] = Bh[ib]; bfl[i] = Bl[ib];
        }
        #pragma unroll
        for (int i = 0; i < 4; ++i)
            #pragma unroll
            for (int j = 0; j < 4; ++j) {
                acc[i][j] = __builtin_amdgcn_mfma_f32_16x16x32_bf16(afh[i], bfh[j], acc[i][j], 0, 0, 0);
                acc[i][j] = __builtin_amdgcn_mfma_f32_16x16x32_bf16(afh[i], bfl[j], acc[i][j], 0, 0, 0);
                acc[i][j] = __builtin_amdgcn_mfma_f32_16x16x32_bf16(afl[i], bfh[j], acc[i][j], 0, 0, 0);
            }
        __syncthreads();
    }

    // Epilogue: D row = d, col = m=(b,s). u0T[b][d][s].
    const int b = m0 >> 11;
    const int s_base = m0 & (SEQ - 1);
    #pragma unroll
    for (int i = 0; i < 4; ++i) {
        #pragma unroll
        for (int r = 0; r < 4; ++r) {
            const int d = d0 + wr + i * 16 + kb * 4 + r;
            const float bb = bias[d];
            float* dst = u0T + (size_t)b * D_IN * SEQ + (size_t)d * SEQ + s_base;
            #pragma unroll
            for (int j = 0; j < 4; ++j)
                dst[wc + j * 16 + lr] = acc[i][j][r] + bb;
        }
    }
}

// ---------------- GEMM2 (MFMA, split-bf16): out = y @ Wout + b_out + x ----------------
__global__ __launch_bounds__(256) void gemm2_mfma(
    const float* __restrict__ yT,
    const unsigned short* __restrict__ Woth, const unsigned short* __restrict__ Wotl,
    const float* __restrict__ bias,   // b_out[n]
    const float* __restrict__ resid,  // x [8192][1024]
    float* __restrict__ out) {
    __shared__ bf16x8 Ah[512], Al[512], Bh[512], Bl[512];
    __shared__ float Yt[BK][132];   // fp32 bounce tile [k][m]

    const int t = threadIdx.x;
    const int w = t >> 6, lane = t & 63;
    const int lr = lane & 15, kb = lane >> 4;
    const int wr = (w >> 1) * 64;   // m quadrant
    const int wc = (w & 1) * 64;    // n quadrant
    const int n0 = blockIdx.x * 128;
    const int m0 = blockIdx.y * 128;
    const int b = m0 >> 11;
    const int s0 = m0 & (SEQ - 1);
    const int sm = t >> 2, sslot = t & 3;
    const int ykl = t >> 3, ymq = (t & 7) * 16;

    f32x4 acc[4][4];
    #pragma unroll
    for (int i = 0; i < 4; ++i)
        #pragma unroll
        for (int j = 0; j < 4; ++j) acc[i][j] = (f32x4)(0.f);

    for (int k0 = 0; k0 < D_IN; k0 += BK) {
        #pragma unroll
        for (int h = 0; h < 2; ++h) {
            const int n = sm + h * 64;
            const int idx = n * 4 + (sslot ^ ((n >> 1) & 3));
            const size_t gb = (size_t)(n0 + n) * D_IN + k0 + sslot * 8;
            Bh[idx] = *reinterpret_cast<const bf16x8*>(Woth + gb);
            Bl[idx] = *reinterpret_cast<const bf16x8*>(Wotl + gb);
        }
        {
            const float* ysrc = yT + (size_t)b * D_IN * SEQ + (size_t)(k0 + ykl) * SEQ + s0 + ymq;
            #pragma unroll
            for (int c = 0; c < 4; ++c) {
                float4 v = *reinterpret_cast<const float4*>(&ysrc[c * 4]);
                *reinterpret_cast<float4*>(&Yt[ykl][ymq + c * 4]) = v;
            }
        }
        __syncthreads();

        // convert y tile -> split-bf16 [m][k-slot] with swizzle
        #pragma unroll
        for (int c = 0; c < 2; ++c) {
            const int sl = (t & 1) * 2 + c;
            const int m = t >> 1;
            bf16x8 vh, vl;
            #pragma unroll
            for (int e = 0; e < 8; ++e) {
                short hsh, lsh;
                split_bf16(Yt[sl * 8 + e][m], hsh, lsh);
                vh[e] = hsh; vl[e] = lsh;
            }
            const int idx = m * 4 + (sl ^ ((m >> 1) & 3));
            Ah[idx] = vh; Al[idx] = vl;
        }
        __syncthreads();

        bf16x8 afh[4], afl[4], bfh[4], bfl[4];
        #pragma unroll
        for (int i = 0; i < 4; ++i) {
            const int m = wr + i * 16 + lr;
            const int ia = m * 4 + (kb ^ ((m >> 1) & 3));
            afh[i] = Ah[ia]; afl[i] = Al[ia];
            const int n = wc + i * 16 + lr;
            const int ib = n * 4 + (kb ^ ((n >> 1) & 3));
            bfh[i] = Bh[ib]; bfl[i] = Bl[ib];
        }
        #pragma unroll
        for (int i = 0; i < 4; ++i)
            #pragma unroll
            for (int j = 0; j < 4; ++j) {
                acc[i][j] = __builtin_amdgcn_mfma_f32_16x16x32_bf16(afh[i], bfh[j], acc[i][j], 0, 0, 0);
                acc[i][j] = __builtin_amdgcn_mfma_f32_16x16x32_bf16(afh[i], bfl[j], acc[i][j], 0, 0, 0);
                acc[i][j] = __builtin_amdgcn_mfma_f32_16x16x32_bf16(afl[i], bfh[j], acc[i][j], 0, 0, 0);
            }
        __syncthreads();
    }

    #pragma unroll
    for (int i = 0; i < 4; ++i) {
        #pragma unroll
        for (int r = 0; r < 4; ++r) {
            const int row = m0 + wr + i * 16 + kb * 4 + r;
            #pragma unroll
            for (int j = 0; j < 4; ++j) {
                const int col = n0 + wc + j * 16 + lr;
                out[(size_t)row * D_MODEL + col] =
                    acc[i][j][r] + bias[col] + resid[(size_t)row * D_MODEL + col];
            }
        }
    }
}

// ---------------- Prep: per-channel scan matrices (unchanged) ----------------
__global__ void prep_kernel(const float* __restrict__ A,
                            const float* __restrict__ Bm,
                            const float* __restrict__ Cm,
                            float* __restrict__ mats) {
    const int d = blockIdx.x;
    const int t = threadIdx.x;
    const int r = t >> 4, sc = t & 15;

    __shared__ float Ash[16][17];
    __shared__ float Mcur[16][17];
    __shared__ float Bv[16], Cv[16], gs[16], cd[16];

    Ash[r][sc] = A[(size_t)d * 256 + r * 16 + sc];
    if (t < 16) { Bv[t] = Bm[d * 16 + t]; Cv[t] = Cm[d * 16 + t]; }
    Mcur[r][sc] = (r == sc) ? 1.f : 0.f;
    __syncthreads();

    float* md = mats + (size_t)d * 1024;

    for (int m = 0; m <= 16; ++m) {
        float g = 0.f, wv = 0.f, acc = 0.f;
        if (m <= 15 && t < 16) {
            #pragma unroll
            for (int rr = 0; rr < 16; ++rr) g = fmaf(Bv[rr], Mcur[rr][t], g);
        }
        if (m >= 1 && sc == 0) {
            #pragma unroll
            for (int ss = 0; ss < 16; ++ss) wv = fmaf(Mcur[r][ss], Cv[ss], wv);
        }
        if (m == 16) md[0 + sc * 16 + r] = Mcur[r][sc];
        if (m < 16) {
            #pragma unroll
            for (int k = 0; k < 16; ++k) acc = fmaf(Mcur[r][k], Ash[k][sc], acc);
        }
        if (m <= 15 && t < 16) { md[256 + t * 16 + (15 - m)] = g; gs[t] = g; }
        if (m >= 1 && sc == 0) md[512 + (m - 1) * 16 + r] = wv;
        __syncthreads();
        if (m <= 15 && t == 0) {
            float c = 0.f;
            #pragma unroll
            for (int ss = 0; ss < 16; ++ss) c = fmaf(gs[ss], Cv[ss], c);
            cd[m] = c;
        }
        if (m < 16) Mcur[r][sc] = acc;
        __syncthreads();
    }
    md[768 + r * 16 + sc] = (sc <= r) ? cd[r - sc] : 0.f;
}

// ---------------- Fused conv + scan, 16 steps per macro-step, in-place (unchanged) --------
__global__ void scan16_kernel(float* __restrict__ u,
                              const float* __restrict__ conv_w,
                              const float* __restrict__ conv_b,
                              const float* __restrict__ mats) {
    const int d = blockIdx.x;
    const int lane = threadIdx.x;
    const int s = lane & 15;
    const int b = lane >> 4;
    const int base = lane & 48;

    const float* md = mats + (size_t)d * 1024;
    float Pt[16], Gt[16], Wt[16], Qt[16];
    #pragma unroll
    for (int q = 0; q < 4; ++q) {
        float4 v;
        v = reinterpret_cast<const float4*>(md + 0   + s * 16)[q];
        Pt[4*q+0]=v.x; Pt[4*q+1]=v.y; Pt[4*q+2]=v.z; Pt[4*q+3]=v.w;
        v = reinterpret_cast<const float4*>(md + 256 + s * 16)[q];
        Gt[4*q+0]=v.x; Gt[4*q+1]=v.y; Gt[4*q+2]=v.z; Gt[4*q+3]=v.w;
        v = reinterpret_cast<const float4*>(md + 512 + s * 16)[q];
        Wt[4*q+0]=v.x; Wt[4*q+1]=v.y; Wt[4*q+2]=v.z; Wt[4*q+3]=v.w;
        v = reinterpret_cast<const float4*>(md + 768 + s * 16)[q];
        Qt[4*q+0]=v.x; Qt[4*q+1]=v.y; Qt[4*q+2]=v.z; Qt[4*q+3]=v.w;
    }

    const float w0 = conv_w[d * 4 + 0];
    const float w1 = conv_w[d * 4 + 1];
    const float w2 = conv_w[d * 4 + 2];
    const float w3 = conv_w[d * 4 + 3];
    const float cb = conv_b[d];

    float hc = 0.f;
    float c1 = 0.f, c2 = 0.f, c3 = 0.f;

    float* up = u + (size_t)b * D_IN * SEQ + (size_t)d * SEQ;

    for (int m = 0; m < SEQ / 16; ++m) {
        const float x = up[16 * m + s];

        float xm1 = __shfl(x, (lane - 1) & 63, 64);
        float xm2 = __shfl(x, (lane - 2) & 63, 64);
        float xm3 = __shfl(x, (lane - 3) & 63, 64);
        if (s == 0) xm1 = c1;
        if (s <= 1) xm2 = (s == 1) ? c1 : c2;
        if (s <= 2) xm3 = (s == 2) ? c1 : ((s == 1) ? c2 : c3);
        const float uval = fmaf(w3, x, fmaf(w2, xm1, fmaf(w1, xm2, fmaf(w0, xm3, cb))));

        const float n1 = __shfl(x, base + 15, 64);
        const float n2 = __shfl(x, base + 14, 64);
        const float n3 = __shfl(x, base + 13, 64);

        float hnA = 0.f, hnB = 0.f, yvA = 0.f, yvB = 0.f;
        #pragma unroll
        for (int rq = 0; rq < 8; ++rq) {
            const float h0 = __shfl(hc, base + 2 * rq + 0, 64);
            const float h1 = __shfl(hc, base + 2 * rq + 1, 64);
            hnA = fmaf(h0, Pt[2 * rq + 0], hnA);
            hnB = fmaf(h1, Pt[2 * rq + 1], hnB);
            yvA = fmaf(h0, Wt[2 * rq + 0], yvA);
            yvB = fmaf(h1, Wt[2 * rq + 1], yvB);
        }
        #pragma unroll
        for (int iq = 0; iq < 8; ++iq) {
            const float u0 = __shfl(uval, base + 2 * iq + 0, 64);
            const float u1 = __shfl(uval, base + 2 * iq + 1, 64);
            hnA = fmaf(u0, Gt[2 * iq + 0], hnA);
            hnB = fmaf(u1, Gt[2 * iq + 1], hnB);
            yvA = fmaf(u0, Qt[2 * iq + 0], yvA);
            yvB = fmaf(u1, Qt[2 * iq + 1], yvB);
        }
        hc = hnA + hnB;
        up[16 * m + s] = yvA + yvB;
        c1 = n1; c2 = n2; c3 = n3;
    }
}

extern "C" void kernel_launch(void* const* d_in, const int* in_sizes, int n_in,
                              void* d_out, int out_size, void* d_ws, size_t ws_size,
                              hipStream_t stream) {
    const float* x      = (const float*)d_in[0];
    const float* norm_w = (const float*)d_in[1];
    const float* Win    = (const float*)d_in[2];
    const float* b_in   = (const float*)d_in[3];
    const float* conv_w = (const float*)d_in[4];
    const float* conv_b = (const float*)d_in[5];
    const float* A      = (const float*)d_in[6];
    const float* Bm     = (const float*)d_in[7];
    const float* Cm     = (const float*)d_in[8];
    const float* Wout   = (const float*)d_in[9];
    const float* b_out  = (const float*)d_in[10];
    float* out = (float*)d_out;

    // ws: [0,64M) u0T/yT fp32 | [64,72M) mats | [72,80M) Win^T hi/lo | [80,88M) Wout^T hi/lo
    char* W = (char*)d_ws;
    float* u0T  = (float*)W;
    float* mats = (float*)(W + (size_t)(64 << 20));
    unsigned short* Wth  = (unsigned short*)(W + (size_t)(72 << 20));
    unsigned short* Wtl  = (unsigned short*)(W + (size_t)(76 << 20));
    unsigned short* Woth = (unsigned short*)(W + (size_t)(80 << 20));
    unsigned short* Wotl = (unsigned short*)(W + (size_t)(84 << 20));

    // d_out doubles as h hi/lo scratch (dead before gemm2 writes out)
    unsigned short* hh = (unsigned short*)d_out;
    unsigned short* hl = hh + (size_t)NROWS * D_MODEL;

    prep_kernel<<<D_IN, 256, 0, stream>>>(A, Bm, Cm, mats);

    {   // Win [1024][2048] -> Wt [2048][1024] hi/lo
        dim3 g(D_IN / 64, D_MODEL / 64, 1);
        transpose_cast_kernel<<<g, 256, 0, stream>>>(Win, Wth, Wtl, D_MODEL, D_IN);
    }
    {   // Wout [2048][1024] -> Wot [1024][2048] hi/lo
        dim3 g(D_MODEL / 64, D_IN / 64, 1);
        transpose_cast_kernel<<<g, 256, 0, stream>>>(Wout, Woth, Wotl, D_IN, D_MODEL);
    }

    rmsnorm_kernel<<<NROWS, 256, 0, stream>>>(x, norm_w, hh, hl);

    {   // u0T[b][d][s] = h @ Win + b_in
        dim3 grid(D_IN / 128, NROWS / 128);
        gemm1_mfma<<<grid, 256, 0, stream>>>(Wth, Wtl, hh, hl, b_in, u0T);
    }

    scan16_kernel<<<D_IN, 64, 0, stream>>>(u0T, conv_w, conv_b, mats);

    {   // out = y @ Wout + b_out + x
        dim3 grid(D_MODEL / 128, NROWS / 128);
        gemm2_mfma<<<grid, 256, 0, stream>>>(u0T, Woth, Wotl, b_out, x, out);
    }
}

// Round 5
// 360.470 us; speedup vs baseline: 5.8704x; 1.1700x over previous
//
#include <hip/hip_runtime.h>
#include <cstddef>

#define D_MODEL 1024
#define D_IN    2048
#define D_STATE 16
#define BATCH   4
#define SEQ     2048
#define NROWS   (BATCH * SEQ)   // 8192

typedef __attribute__((ext_vector_type(8))) short bf16x8;
typedef __attribute__((ext_vector_type(4))) float f32x4;
typedef unsigned short u16;

// Swizzle convention (shared by ALL producers and the GEMM readers):
// within each 64-elem k-window (8 chunks of 8 bf16 = 16B), logical chunk lc of
// row r is stored at physical chunk position lc ^ (r & 7).  global_load_lds
// copies linearly, so LDS inherits the swizzle; ds_read_b128 applies the same
// XOR => 16 consecutive rows hit 8 distinct 4-bank groups (2-way = free).

__device__ __forceinline__ void split_bf16(float f, short& hi, short& lo) {
    unsigned int u = __float_as_uint(f);
    hi = (short)(u >> 16);
    float fhi = __uint_as_float(u & 0xFFFF0000u);
    lo = (short)(__float_as_uint(f - fhi) >> 16);
}

__device__ __forceinline__ void gload16(const void* g, void* l) {
    __builtin_amdgcn_global_load_lds(
        (const __attribute__((address_space(1))) unsigned int*)g,
        (__attribute__((address_space(3))) unsigned int*)l, 16, 0, 0);
}

// ---------------- RMSNorm -> swizzled split-bf16 hi/lo ----------------
// 128 threads = 1 row; thread = one 8-elem chunk.
__global__ void rmsnorm_kernel(const float* __restrict__ x,
                               const float* __restrict__ w,
                               u16* __restrict__ hh, u16* __restrict__ hl) {
    const int row = blockIdx.x;
    const int c = threadIdx.x;              // chunk 0..127
    const float* xr = x + (size_t)row * D_MODEL;

    float4 va = reinterpret_cast<const float4*>(xr)[c * 2 + 0];
    float4 vb = reinterpret_cast<const float4*>(xr)[c * 2 + 1];
    float ss = va.x*va.x + va.y*va.y + va.z*va.z + va.w*va.w
             + vb.x*vb.x + vb.y*vb.y + vb.z*vb.z + vb.w*vb.w;
    #pragma unroll
    for (int off = 32; off > 0; off >>= 1) ss += __shfl_down(ss, off, 64);

    __shared__ float ws2[2];
    if ((threadIdx.x & 63) == 0) ws2[threadIdx.x >> 6] = ss;
    __syncthreads();
    const float tot = ws2[0] + ws2[1];
    const float scale = rsqrtf(tot * (1.0f / D_MODEL) + 1e-6f);

    float4 wa = reinterpret_cast<const float4*>(w)[c * 2 + 0];
    float4 wb = reinterpret_cast<const float4*>(w)[c * 2 + 1];
    float o[8] = { va.x*scale*wa.x, va.y*scale*wa.y, va.z*scale*wa.z, va.w*scale*wa.w,
                   vb.x*scale*wb.x, vb.y*scale*wb.y, vb.z*scale*wb.z, vb.w*scale*wb.w };
    bf16x8 vh, vl;
    #pragma unroll
    for (int e = 0; e < 8; ++e) { short h, l; split_bf16(o[e], h, l); vh[e] = h; vl[e] = l; }

    const size_t eb = (size_t)row * D_MODEL + (size_t)(c & ~7) * 8
                    + (size_t)((c & 7) ^ (row & 7)) * 8;
    *reinterpret_cast<bf16x8*>(&hh[eb]) = vh;
    *reinterpret_cast<bf16x8*>(&hl[eb]) = vl;
}

// ------------- transpose + split-cast (weights): in[R][C] f32 -> out[c][R] swizzled -------------
__global__ void transpose_cast_kernel(const float* __restrict__ in,
                                      u16* __restrict__ oh, u16* __restrict__ ol,
                                      int R, int C) {
    __shared__ float T[64][65];
    const int r0 = blockIdx.y * 64, c0 = blockIdx.x * 64;
    const int t = threadIdx.x;

    #pragma unroll
    for (int i = 0; i < 4; ++i) {
        const int r = (t >> 4) + i * 16;
        float4 v = *reinterpret_cast<const float4*>(
            &in[(size_t)(r0 + r) * C + c0 + (t & 15) * 4]);
        T[r][(t & 15) * 4 + 0] = v.x;
        T[r][(t & 15) * 4 + 1] = v.y;
        T[r][(t & 15) * 4 + 2] = v.z;
        T[r][(t & 15) * 4 + 3] = v.w;
    }
    __syncthreads();

    #pragma unroll
    for (int g = 0; g < 2; ++g) {
        const int idx = t + g * 256;   // 0..511
        const int c  = idx >> 3;       // out-row local 0..63
        const int rg = idx & 7;        // k-chunk within this 64-window
        bf16x8 vh, vl;
        #pragma unroll
        for (int e = 0; e < 8; ++e) {
            short h, l;
            split_bf16(T[rg * 8 + e][c], h, l);
            vh[e] = h; vl[e] = l;
        }
        const int orow = c0 + c;
        const size_t ob = (size_t)orow * R + r0 + (size_t)(rg ^ (orow & 7)) * 8;
        *reinterpret_cast<bf16x8*>(&oh[ob]) = vh;
        *reinterpret_cast<bf16x8*>(&ol[ob]) = vl;
    }
}

// ---------------- Unified split-bf16 GEMM, global_load_lds staged ----------------
// Tile 128x128, BK=64, 4 waves. Wave w stages array w (Ah/Al/Bh/Bl, 16KB each).
// EPI=0: A=Win^T(rows d = bx*128), B=h(rows m = by*128) -> u0T[b][d][s] + b_in
// EPI=1: A=y2  (rows m = by*128), B=Wout^T(rows n = bx*128) -> out + b_out + x
template<int KTOT, int EPI>
__global__ __launch_bounds__(256, 2) void gemm_gll(
    const u16* __restrict__ Agh, const u16* __restrict__ Agl,
    const u16* __restrict__ Bgh, const u16* __restrict__ Bgl,
    const float* __restrict__ bias, const float* __restrict__ resid,
    float* __restrict__ outp) {
    __shared__ __align__(16) char lds[65536];

    const int t = threadIdx.x;
    const int wv = t >> 6, lane = t & 63;
    const int lr = lane & 15, kb = lane >> 4;
    const int wr = (wv >> 1) * 64;
    const int wc = (wv & 1) * 64;
    const int a_r0 = (EPI == 0 ? blockIdx.x : blockIdx.y) * 128;
    const int b_r0 = (EPI == 0 ? blockIdx.y : blockIdx.x) * 128;

    const u16* garr = (wv == 0) ? Agh : (wv == 1) ? Agl : (wv == 2) ? Bgh : Bgl;
    const int grow0 = (wv < 2) ? a_r0 : b_r0;
    char* lbase = lds + wv * 16384;
    const u16* gsrc = garr + (size_t)(grow0 + (lane >> 3)) * KTOT + (lane & 7) * 8;

    f32x4 acc[4][4];
    #pragma unroll
    for (int i = 0; i < 4; ++i)
        #pragma unroll
        for (int j = 0; j < 4; ++j) acc[i][j] = (f32x4)(0.f);

    for (int k0 = 0; k0 < KTOT; k0 += 64) {
        if (k0) __syncthreads();             // prev compute done before overwrite
        const u16* gk = gsrc + k0;
        #pragma unroll
        for (int sgi = 0; sgi < 16; ++sgi)
            gload16(gk + (size_t)sgi * 8 * KTOT, lbase + sgi * 1024);
        __syncthreads();                     // compiler drains vmcnt before barrier

        #pragma unroll
        for (int ks = 0; ks < 2; ++ks) {
            bf16x8 afh[4], afl[4], bfh[4], bfl[4];
            #pragma unroll
            for (int i = 0; i < 4; ++i) {
                const int ra = wr + i * 16 + lr;
                const int oa = (ra << 7) + (((ks * 4 + kb) ^ (ra & 7)) << 4);
                afh[i] = *reinterpret_cast<const bf16x8*>(lds + oa);
                afl[i] = *reinterpret_cast<const bf16x8*>(lds + 16384 + oa);
                const int rb = wc + i * 16 + lr;
                const int ob = (rb << 7) + (((ks * 4 + kb) ^ (rb & 7)) << 4);
                bfh[i] = *reinterpret_cast<const bf16x8*>(lds + 32768 + ob);
                bfl[i] = *reinterpret_cast<const bf16x8*>(lds + 49152 + ob);
            }
            #pragma unroll
            for (int i = 0; i < 4; ++i)
                #pragma unroll
                for (int j = 0; j < 4; ++j) {
                    acc[i][j] = __builtin_amdgcn_mfma_f32_16x16x32_bf16(afh[i], bfh[j], acc[i][j], 0, 0, 0);
                    acc[i][j] = __builtin_amdgcn_mfma_f32_16x16x32_bf16(afh[i], bfl[j], acc[i][j], 0, 0, 0);
                    acc[i][j] = __builtin_amdgcn_mfma_f32_16x16x32_bf16(afl[i], bfh[j], acc[i][j], 0, 0, 0);
                }
        }
    }

    if (EPI == 0) {
        const int b = b_r0 >> 11;
        const int s_base = b_r0 & (SEQ - 1);
        #pragma unroll
        for (int i = 0; i < 4; ++i) {
            #pragma unroll
            for (int r = 0; r < 4; ++r) {
                const int d = a_r0 + wr + i * 16 + kb * 4 + r;
                const float bb = bias[d];
                float* dst = outp + (size_t)b * D_IN * SEQ + (size_t)d * SEQ + s_base;
                #pragma unroll
                for (int j = 0; j < 4; ++j)
                    dst[wc + j * 16 + lr] = acc[i][j][r] + bb;
            }
        }
    } else {
        #pragma unroll
        for (int i = 0; i < 4; ++i) {
            #pragma unroll
            for (int r = 0; r < 4; ++r) {
                const int row = a_r0 + wr + i * 16 + kb * 4 + r;
                #pragma unroll
                for (int j = 0; j < 4; ++j) {
                    const int col = b_r0 + wc + j * 16 + lr;
                    outp[(size_t)row * D_MODEL + col] =
                        acc[i][j][r] + bias[col] + resid[(size_t)row * D_MODEL + col];
                }
            }
        }
    }
}

// ---------------- Prep: per-channel scan matrices (unchanged math) ----------------
__global__ void prep_kernel(const float* __restrict__ A,
                            const float* __restrict__ Bm,
                            const float* __restrict__ Cm,
                            float* __restrict__ mats) {
    const int d = blockIdx.x;
    const int t = threadIdx.x;
    const int r = t >> 4, sc = t & 15;

    __shared__ float Ash[16][17];
    __shared__ float Mcur[16][17];
    __shared__ float Bv[16], Cv[16], gs[16], cd[16];

    Ash[r][sc] = A[(size_t)d * 256 + r * 16 + sc];
    if (t < 16) { Bv[t] = Bm[d * 16 + t]; Cv[t] = Cm[d * 16 + t]; }
    Mcur[r][sc] = (r == sc) ? 1.f : 0.f;
    __syncthreads();

    float* md = mats + (size_t)d * 1024;

    for (int m = 0; m <= 16; ++m) {
        float g = 0.f, wv = 0.f, acc = 0.f;
        if (m <= 15 && t < 16) {
            #pragma unroll
            for (int rr = 0; rr < 16; ++rr) g = fmaf(Bv[rr], Mcur[rr][t], g);
        }
        if (m >= 1 && sc == 0) {
            #pragma unroll
            for (int ss = 0; ss < 16; ++ss) wv = fmaf(Mcur[r][ss], Cv[ss], wv);
        }
        if (m == 16) md[0 + sc * 16 + r] = Mcur[r][sc];
        if (m < 16) {
            #pragma unroll
            for (int k = 0; k < 16; ++k) acc = fmaf(Mcur[r][k], Ash[k][sc], acc);
        }
        if (m <= 15 && t < 16) { md[256 + t * 16 + (15 - m)] = g; gs[t] = g; }
        if (m >= 1 && sc == 0) md[512 + (m - 1) * 16 + r] = wv;
        __syncthreads();
        if (m <= 15 && t == 0) {
            float c = 0.f;
            #pragma unroll
            for (int ss = 0; ss < 16; ++ss) c = fmaf(gs[ss], Cv[ss], c);
            cd[m] = c;
        }
        if (m < 16) Mcur[r][sc] = acc;
        __syncthreads();
    }
    md[768 + r * 16 + sc] = (sc <= r) ? cd[r - sc] : 0.f;
}

// ------- Fused conv + scan, 16 t per macro-step; 8 waves = 8 channels per block. -------
// Output: y split-bf16, TRANSPOSED [m=(b,s)][k=d] with baked swizzle (gemm2 A-operand).
__global__ __launch_bounds__(512) void scan8_kernel(
    const float* __restrict__ u,            // u0T [b][d][s] fp32
    const float* __restrict__ conv_w, const float* __restrict__ conv_b,
    const float* __restrict__ mats,
    u16* __restrict__ y2h, u16* __restrict__ y2l) {
    const int wv = threadIdx.x >> 6;        // 0..7
    const int lane = threadIdx.x & 63;
    const int d = blockIdx.x * 8 + wv;
    const int s = lane & 15;
    const int b = lane >> 4;
    const int base = lane & 48;

    __shared__ float Yt[2][8][64];

    const float* md = mats + (size_t)d * 1024;
    float Pt[16], Gt[16], Wt[16], Qt[16];
    #pragma unroll
    for (int q = 0; q < 4; ++q) {
        float4 v;
        v = reinterpret_cast<const float4*>(md + 0   + s * 16)[q];
        Pt[4*q+0]=v.x; Pt[4*q+1]=v.y; Pt[4*q+2]=v.z; Pt[4*q+3]=v.w;
        v = reinterpret_cast<const float4*>(md + 256 + s * 16)[q];
        Gt[4*q+0]=v.x; Gt[4*q+1]=v.y; Gt[4*q+2]=v.z; Gt[4*q+3]=v.w;
        v = reinterpret_cast<const float4*>(md + 512 + s * 16)[q];
        Wt[4*q+0]=v.x; Wt[4*q+1]=v.y; Wt[4*q+2]=v.z; Wt[4*q+3]=v.w;
        v = reinterpret_cast<const float4*>(md + 768 + s * 16)[q];
        Qt[4*q+0]=v.x; Qt[4*q+1]=v.y; Qt[4*q+2]=v.z; Qt[4*q+3]=v.w;
    }

    const float w0 = conv_w[d * 4 + 0];
    const float w1 = conv_w[d * 4 + 1];
    const float w2 = conv_w[d * 4 + 2];
    const float w3 = conv_w[d * 4 + 3];
    const float cb = conv_b[d];

    float hc = 0.f;
    float c1 = 0.f, c2 = 0.f, c3 = 0.f;

    const float* up = u + (size_t)b * D_IN * SEQ + (size_t)d * SEQ;
    const int w64 = (blockIdx.x * 8) & ~63;   // k-window base (elems)
    const int lc  = blockIdx.x & 7;           // logical chunk within window

    for (int m = 0; m < SEQ / 16; ++m) {
        const float x = up[16 * m + s];

        float xm1 = __shfl(x, (lane - 1) & 63, 64);
        float xm2 = __shfl(x, (lane - 2) & 63, 64);
        float xm3 = __shfl(x, (lane - 3) & 63, 64);
        if (s == 0) xm1 = c1;
        if (s <= 1) xm2 = (s == 1) ? c1 : c2;
        if (s <= 2) xm3 = (s == 2) ? c1 : ((s == 1) ? c2 : c3);
        const float uval = fmaf(w3, x, fmaf(w2, xm1, fmaf(w1, xm2, fmaf(w0, xm3, cb))));

        const float n1 = __shfl(x, base + 15, 64);
        const float n2 = __shfl(x, base + 14, 64);
        const float n3 = __shfl(x, base + 13, 64);

        float hnA = 0.f, hnB = 0.f, yvA = 0.f, yvB = 0.f;
        #pragma unroll
        for (int rq = 0; rq < 8; ++rq) {
            const float h0 = __shfl(hc, base + 2 * rq + 0, 64);
            const float h1 = __shfl(hc, base + 2 * rq + 1, 64);
            hnA = fmaf(h0, Pt[2 * rq + 0], hnA);
            hnB = fmaf(h1, Pt[2 * rq + 1], hnB);
            yvA = fmaf(h0, Wt[2 * rq + 0], yvA);
            yvB = fmaf(h1, Wt[2 * rq + 1], yvB);
        }
        #pragma unroll
        for (int iq = 0; iq < 8; ++iq) {
            const float u0 = __shfl(uval, base + 2 * iq + 0, 64);
            const float u1 = __shfl(uval, base + 2 * iq + 1, 64);
            hnA = fmaf(u0, Gt[2 * iq + 0], hnA);
            hnB = fmaf(u1, Gt[2 * iq + 1], hnB);
            yvA = fmaf(u0, Qt[2 * iq + 0], yvA);
            yvB = fmaf(u1, Qt[2 * iq + 1], yvB);
        }
        hc = hnA + hnB;
        c1 = n1; c2 = n2; c3 = n3;

        Yt[m & 1][wv][lane] = yvA + yvB;
        __syncthreads();

        // write phase: per wave, 16 lanes cover m-values [wv*8, wv*8+8) x two 4-d halves
        if (lane < 16) {
            const int mm = wv * 8 + (lane & 7);     // 0..63 = (b',s')
            const int half = lane >> 3;             // d-sub [half*4, half*4+4)
            const int bb = mm >> 4, ssg = mm & 15;
            const size_t orow = (size_t)bb * SEQ + 16 * m + ssg;
            short4 vh, vl;
            split_bf16(Yt[m & 1][half * 4 + 0][mm], vh.x, vl.x);
            split_bf16(Yt[m & 1][half * 4 + 1][mm], vh.y, vl.y);
            split_bf16(Yt[m & 1][half * 4 + 2][mm], vh.z, vl.z);
            split_bf16(Yt[m & 1][half * 4 + 3][mm], vh.w, vl.w);
            const size_t eb = orow * D_IN + w64
                            + (size_t)((lc ^ (int)(orow & 7)) << 3) + half * 4;
            *reinterpret_cast<short4*>(&y2h[eb]) = vh;
            *reinterpret_cast<short4*>(&y2l[eb]) = vl;
        }
    }
}

extern "C" void kernel_launch(void* const* d_in, const int* in_sizes, int n_in,
                              void* d_out, int out_size, void* d_ws, size_t ws_size,
                              hipStream_t stream) {
    const float* x      = (const float*)d_in[0];
    const float* norm_w = (const float*)d_in[1];
    const float* Win    = (const float*)d_in[2];
    const float* b_in   = (const float*)d_in[3];
    const float* conv_w = (const float*)d_in[4];
    const float* conv_b = (const float*)d_in[5];
    const float* A      = (const float*)d_in[6];
    const float* Bm     = (const float*)d_in[7];
    const float* Cm     = (const float*)d_in[8];
    const float* Wout   = (const float*)d_in[9];
    const float* b_out  = (const float*)d_in[10];
    float* out = (float*)d_out;

    // ws (128MB total), phase-overlapped:
    //   [0,64M):  u0T fp32 (gemm1 out, scan in)   -> later Woth@[0,4M), Wotl@[4,8M)
    //   [64,128M): Wth@[64,68M), Wtl@[68,72M)     -> later y2h@[64,96M), y2l@[96,128M)
    // d_out: hh/hl (rmsnorm->gemm1) -> mats (prep->scan) -> final output (gemm2)
    char* W = (char*)d_ws;
    float* u0T = (float*)W;
    u16* Wth  = (u16*)(W + ((size_t)64 << 20));
    u16* Wtl  = (u16*)(W + ((size_t)68 << 20));
    u16* y2h  = (u16*)(W + ((size_t)64 << 20));
    u16* y2l  = (u16*)(W + ((size_t)96 << 20));
    u16* Woth = (u16*)W;
    u16* Wotl = (u16*)(W + ((size_t)4 << 20));
    u16* hh = (u16*)d_out;
    u16* hl = hh + (size_t)NROWS * D_MODEL;
    float* mats = (float*)d_out;

    // 1) Win [1024][2048] -> Win^T split/swizzled [2048][1024]
    {
        dim3 g(D_IN / 64, D_MODEL / 64);
        transpose_cast_kernel<<<g, 256, 0, stream>>>(Win, Wth, Wtl, D_MODEL, D_IN);
    }
    // 2) RMSNorm -> h split/swizzled (in d_out)
    rmsnorm_kernel<<<NROWS, 128, 0, stream>>>(x, norm_w, hh, hl);
    // 3) u0T[b][d][s] = h @ Win + b_in
    {
        dim3 grid(D_IN / 128, NROWS / 128);
        gemm_gll<D_MODEL, 0><<<grid, 256, 0, stream>>>(Wth, Wtl, hh, hl, b_in, nullptr, u0T);
    }
    // 4) scan matrices -> mats (d_out; hh/hl dead)
    prep_kernel<<<D_IN, 256, 0, stream>>>(A, Bm, Cm, mats);
    // 5) conv+scan -> y2 split/swizzled transposed [m][d] (Wt region dead)
    scan8_kernel<<<D_IN / 8, 512, 0, stream>>>(u0T, conv_w, conv_b, mats, y2h, y2l);
    // 6) Wout [2048][1024] -> Wout^T split/swizzled [1024][2048] (u0T dead)
    {
        dim3 g(D_MODEL / 64, D_IN / 64);
        transpose_cast_kernel<<<g, 256, 0, stream>>>(Wout, Woth, Wotl, D_IN, D_MODEL);
    }
    // 7) out = y @ Wout + b_out + x (mats dead)
    {
        dim3 grid(D_MODEL / 128, NROWS / 128);
        gemm_gll<D_IN, 1><<<grid, 256, 0, stream>>>(y2h, y2l, Woth, Wotl, b_out, x, out);
    }
}